// Round 10
// baseline (449.550 us; speedup 1.0000x reference)
//
#include <hip/hip_runtime.h>

#define B_  32
#define S_  1024
#define H_  1024
#define V_  50257

typedef __attribute__((ext_vector_type(8))) short bf16x8;
typedef __attribute__((ext_vector_type(4))) float f32x4;
typedef __attribute__((ext_vector_type(8))) unsigned short u16x8;

__device__ __forceinline__ unsigned short f2b(float f) {
  union { float f; unsigned u; } v; v.f = f;
  unsigned r = 0x7FFFu + ((v.u >> 16) & 1u);
  return (unsigned short)((v.u + r) >> 16);
}
__device__ __forceinline__ float b2f(unsigned short h) {
  union { unsigned u; float f; } v; v.u = ((unsigned)h) << 16;
  return v.f;
}

__device__ __forceinline__ void async16(void* lds, const void* g) {
  typedef __attribute__((address_space(3))) void as3_void;
  typedef __attribute__((address_space(1))) void as1_void;
  as3_void* l = (as3_void*)(unsigned)(unsigned long long)lds;
  const as1_void* s = (const as1_void*)(unsigned long long)g;
  __builtin_amdgcn_global_load_lds(s, l, 16, 0, 0);
}

// ---------- fused prologue: enc conv (blocks 0..16383) + wa1 conv/part2 ----------
__global__ void prologue_kernel(const float* __restrict__ enc, unsigned short* __restrict__ enc_bf,
                                const float* __restrict__ wa1, const float* __restrict__ hidden,
                                const float* __restrict__ b_a1,
                                unsigned short* __restrict__ wa1_bf, float* __restrict__ part2) {
  __shared__ float wrow[H_];
  int tid = threadIdx.x;
  if (blockIdx.x < 16384) {
    size_t i = ((size_t)blockIdx.x * 256 + tid) * 8;
    float4 v0 = *(const float4*)(enc + i);
    float4 v1 = *(const float4*)(enc + i + 4);
    u16x8 o;
    o[0]=f2b(v0.x); o[1]=f2b(v0.y); o[2]=f2b(v0.z); o[3]=f2b(v0.w);
    o[4]=f2b(v1.x); o[5]=f2b(v1.y); o[6]=f2b(v1.z); o[7]=f2b(v1.w);
    *(u16x8*)(enc_bf + i) = o;
    return;
  }
  int h = blockIdx.x - 16384;
  {
    int c = tid * 4;
    float4 v = *(const float4*)(wa1 + (size_t)h * 2048 + c);
    ushort4 o;
    o.x = f2b(v.x); o.y = f2b(v.y); o.z = f2b(v.z); o.w = f2b(v.w);
    *(ushort4*)(wa1_bf + (size_t)h * 1024 + c) = o;
  }
  {
    int c = tid * 4;
    float4 v = *(const float4*)(wa1 + (size_t)h * 2048 + 1024 + c);
    wrow[c] = v.x; wrow[c+1] = v.y; wrow[c+2] = v.z; wrow[c+3] = v.w;
  }
  __syncthreads();
  int wave = tid >> 6, lane = tid & 63;
  float bias = b_a1[h];
  for (int bb = 0; bb < 8; ++bb) {
    int b = wave * 8 + bb;
    float acc = 0.f;
    for (int k = lane; k < H_; k += 64) acc += wrow[k] * hidden[b * H_ + k];
    #pragma unroll
    for (int off = 32; off; off >>= 1) acc += __shfl_xor(acc, off);
    if (lane == 0) part2[b * H_ + h] = acc + bias;
  }
}

// ---------- scores GEMM v4: LDS-FREE, barrier-free K-loop ----------
// 128x128 tile, 4 waves (2x2 of 64x64). A and B fragments loaded straight from global
// (A streams HBM/L3; B = 2MB, L2-resident). Per-lane 16B gather matches the MFMA A/B
// fragment layout exactly: lane(l15,l16) <- row(l15)*1024 + kt + l16*8.
// Explicit ping-pong (a0/b0 vs a1/b1, named regs per rule #20) overlaps next-step loads
// with current MFMAs. Zero barriers -> waves free-run; fetch concurrency = all resident
// waves instead of 2.3 lockstep blocks.
#define LDF(AV, BV, KT) { \
  _Pragma("unroll") for (int mi = 0; mi < 4; ++mi) AV[mi] = *(const bf16x8*)(ap[mi] + (KT)); \
  _Pragma("unroll") for (int ni = 0; ni < 4; ++ni) BV[ni] = *(const bf16x8*)(bp[ni] + (KT)); }

#define FMAQ(AV, BV) { \
  _Pragma("unroll") for (int mi = 0; mi < 4; ++mi) \
    _Pragma("unroll") for (int ni = 0; ni < 4; ++ni) \
      acc[mi][ni] = __builtin_amdgcn_mfma_f32_16x16x32_bf16(AV[mi], BV[ni], acc[mi][ni], 0, 0, 0); }

__global__ __launch_bounds__(256) void scores_nolds(
    const unsigned short* __restrict__ A,   // enc_bf [32768][1024]
    const unsigned short* __restrict__ Bm,  // wa1_bf [1024][1024]
    const float* __restrict__ part2,        // [32][1024]
    const float* __restrict__ wa2,          // [1024]
    float* __restrict__ partials)           // [32768][16]
{
  const int tid = threadIdx.x;
  const int wave = tid >> 6, lane = tid & 63;
  const int wr = wave >> 1, wc = wave & 1;
  const int l15 = lane & 15, l16 = lane >> 4;
  const int bn = blockIdx.x, bm = blockIdx.y;   // bn fastest: 8 bn-blocks per bm adjacent -> L3 reuse

  const unsigned short* ap[4];
  const unsigned short* bp[4];
  #pragma unroll
  for (int mi = 0; mi < 4; ++mi)
    ap[mi] = A + (size_t)(bm * 128 + wr * 64 + mi * 16 + l15) * 1024 + l16 * 8;
  #pragma unroll
  for (int ni = 0; ni < 4; ++ni)
    bp[ni] = Bm + (size_t)(bn * 128 + wc * 64 + ni * 16 + l15) * 1024 + l16 * 8;

  f32x4 acc[4][4];
  #pragma unroll
  for (int mi = 0; mi < 4; ++mi)
    #pragma unroll
    for (int ni = 0; ni < 4; ++ni) acc[mi][ni] = (f32x4){0.f, 0.f, 0.f, 0.f};

  bf16x8 a0[4], b0[4], a1[4], b1[4];
  LDF(a0, b0, 0);
  #pragma unroll 1
  for (int kt = 0; kt < 960; kt += 64) {
    LDF(a1, b1, kt + 32);
    FMAQ(a0, b0);
    LDF(a0, b0, kt + 64);
    FMAQ(a1, b1);
  }
  LDF(a1, b1, 992);
  FMAQ(a0, b0);       // kt = 960
  FMAQ(a1, b1);       // kt = 992

  // fused epilogue: partials[row][bn*2+wc] = sum over this 64-col group of wa2*tanh(acc+part2)
  const int b = bm >> 3;   // 128 rows/tile, 1024 rows/batch
  float w2[4], p2[4];
  #pragma unroll
  for (int ni = 0; ni < 4; ++ni) {
    int col = bn * 128 + wc * 64 + ni * 16 + l15;
    w2[ni] = wa2[col];
    p2[ni] = part2[b * H_ + col];
  }
  #pragma unroll
  for (int mi = 0; mi < 4; ++mi) {
    #pragma unroll
    for (int r = 0; r < 4; ++r) {
      float s = 0.f;
      #pragma unroll
      for (int ni = 0; ni < 4; ++ni)
        s += w2[ni] * tanhf(acc[mi][ni][r] + p2[ni]);
      s += __shfl_xor(s, 1); s += __shfl_xor(s, 2);
      s += __shfl_xor(s, 4); s += __shfl_xor(s, 8);
      if (l15 == 0) {
        int row = bm * 128 + wr * 64 + mi * 16 + l16 * 4 + r;
        partials[(size_t)row * 16 + bn * 2 + wc] = s;
      }
    }
  }
}

// ---------- fused softmax + context chunk: block (sc, b) ----------
__global__ __launch_bounds__(256) void smctx_kernel(
    const float* __restrict__ partials, const unsigned short* __restrict__ encbf,
    float* __restrict__ ctxp) {
  int sc = blockIdx.x, b = blockIdx.y, tid = threadIdx.x;
  int lane = tid & 63, wid = tid >> 6;
  __shared__ float att[1024];
  __shared__ float red[4];
  float scv[4];
  float mx = -1e30f;
  #pragma unroll
  for (int j = 0; j < 4; ++j) {
    int r = tid * 4 + j;
    const float4* p = (const float4*)(partials + ((size_t)b * 1024 + r) * 16);
    float s = 0.f;
    #pragma unroll
    for (int i = 0; i < 4; ++i) { float4 v = p[i]; s += v.x + v.y + v.z + v.w; }
    scv[j] = s; mx = fmaxf(mx, s);
  }
  #pragma unroll
  for (int off = 32; off; off >>= 1) mx = fmaxf(mx, __shfl_xor(mx, off));
  if (lane == 0) red[wid] = mx;
  __syncthreads();
  float M = fmaxf(fmaxf(red[0], red[1]), fmaxf(red[2], red[3]));
  float ssum = 0.f;
  #pragma unroll
  for (int j = 0; j < 4; ++j) { float e = expf(scv[j] - M); att[tid*4+j] = e; ssum += e; }
  #pragma unroll
  for (int off = 32; off; off >>= 1) ssum += __shfl_xor(ssum, off);
  __syncthreads();
  if (lane == 0) red[wid] = ssum;
  __syncthreads();
  float inv = 1.f / (red[0] + red[1] + red[2] + red[3]);
  int h4 = tid * 4;
  float a0 = 0, a1 = 0, a2 = 0, a3 = 0;
  const unsigned short* base = encbf + (size_t)b * S_ * H_ + h4;
  #pragma unroll 4
  for (int i = 0; i < 64; ++i) {
    float w = att[sc * 64 + i] * inv;
    ushort4 ev = *(const ushort4*)(base + (size_t)(sc * 64 + i) * H_);
    a0 += w * b2f(ev.x); a1 += w * b2f(ev.y); a2 += w * b2f(ev.z); a3 += w * b2f(ev.w);
  }
  float4 o = {a0, a1, a2, a3};
  *(float4*)(ctxp + (size_t)(sc * B_ + b) * H_ + h4) = o;
}

// ---------- W_c GEMM with inline ec construction: block (nb, kc) ----------
__global__ __launch_bounds__(256) void wc_gemm(
    const int* __restrict__ word, const float* __restrict__ emb,
    const float* __restrict__ ctxp, const float* __restrict__ Wc,
    float* __restrict__ xp) {
  int nb = blockIdx.x, kc = blockIdx.y, tid = threadIdx.x;
  __shared__ unsigned short A_lds[32][136];
  {
    int b = tid >> 3, cg = tid & 7;
    int c0 = cg * 16;
    if (kc < 8) {
      int w = word[b];
      const float* er = emb + (size_t)w * H_ + kc * 128 + c0;
      #pragma unroll
      for (int c = 0; c < 16; c += 4) {
        float4 v = *(const float4*)(er + c);
        ushort4 o; o.x = f2b(v.x); o.y = f2b(v.y); o.z = f2b(v.z); o.w = f2b(v.w);
        *(ushort4*)&A_lds[b][c0 + c] = o;
      }
    } else {
      int h0 = (kc - 8) * 128 + c0;
      #pragma unroll
      for (int c = 0; c < 16; c += 4) {
        float s0 = 0, s1 = 0, s2 = 0, s3 = 0;
        #pragma unroll
        for (int sc = 0; sc < 16; ++sc) {
          float4 v = *(const float4*)(ctxp + ((size_t)(sc * B_ + b)) * H_ + h0 + c);
          s0 += v.x; s1 += v.y; s2 += v.z; s3 += v.w;
        }
        ushort4 o; o.x = f2b(s0); o.y = f2b(s1); o.z = f2b(s2); o.w = f2b(s3);
        *(ushort4*)&A_lds[b][c0 + c] = o;
      }
    }
  }
  __syncthreads();
  int wave = tid >> 6, lane = tid & 63, l15 = lane & 15, l16 = lane >> 4;
  int col = nb * 64 + wave * 16 + l15;
  const float* bp = Wc + (size_t)col * 2048 + kc * 128 + l16 * 8;
  f32x4 acc0 = {0.f,0.f,0.f,0.f}, acc1 = {0.f,0.f,0.f,0.f};
  #pragma unroll
  for (int k = 0; k < 128; k += 32) {
    bf16x8 a0 = *(const bf16x8*)&A_lds[l15][k + l16 * 8];
    bf16x8 a1 = *(const bf16x8*)&A_lds[16 + l15][k + l16 * 8];
    float4 bv0 = *(const float4*)(bp + k);
    float4 bv1 = *(const float4*)(bp + k + 4);
    bf16x8 bb;
    bb[0] = (short)f2b(bv0.x); bb[1] = (short)f2b(bv0.y);
    bb[2] = (short)f2b(bv0.z); bb[3] = (short)f2b(bv0.w);
    bb[4] = (short)f2b(bv1.x); bb[5] = (short)f2b(bv1.y);
    bb[6] = (short)f2b(bv1.z); bb[7] = (short)f2b(bv1.w);
    acc0 = __builtin_amdgcn_mfma_f32_16x16x32_bf16(a0, bb, acc0, 0, 0, 0);
    acc1 = __builtin_amdgcn_mfma_f32_16x16x32_bf16(a1, bb, acc1, 0, 0, 0);
  }
  #pragma unroll
  for (int r = 0; r < 4; ++r) {
    int m = l16 * 4 + r;
    xp[(size_t)(kc * 32 + m) * H_ + col] = acc0[r];
    xp[(size_t)(kc * 32 + 16 + m) * H_ + col] = acc1[r];
  }
}

// ---------- fused W_ih / W_hh GEMM with inline x / hprev construction ----------
__global__ __launch_bounds__(256) void ihhh_gemm(
    const float* __restrict__ xp, const float* __restrict__ b_c,
    const float* __restrict__ hidden,
    const float* __restrict__ W_ih, const float* __restrict__ W_hh,
    float* __restrict__ gip, float* __restrict__ ghp) {
  int nb = blockIdx.x, kc = blockIdx.y, z = blockIdx.z, tid = threadIdx.x;
  __shared__ unsigned short A_lds[32][136];
  {
    int b = tid >> 3, cg = tid & 7;
    int c0 = cg * 16;
    int h0 = kc * 128 + c0;
    if (z == 0) {
      #pragma unroll
      for (int c = 0; c < 16; c += 4) {
        float4 bias = *(const float4*)(b_c + h0 + c);
        float s0 = bias.x, s1 = bias.y, s2 = bias.z, s3 = bias.w;
        #pragma unroll
        for (int sc = 0; sc < 16; ++sc) {
          float4 v = *(const float4*)(xp + ((size_t)(sc * B_ + b)) * H_ + h0 + c);
          s0 += v.x; s1 += v.y; s2 += v.z; s3 += v.w;
        }
        ushort4 o;
        o.x = f2b(fmaxf(s0, 0.f)); o.y = f2b(fmaxf(s1, 0.f));
        o.z = f2b(fmaxf(s2, 0.f)); o.w = f2b(fmaxf(s3, 0.f));
        *(ushort4*)&A_lds[b][c0 + c] = o;
      }
    } else {
      #pragma unroll
      for (int c = 0; c < 16; c += 4) {
        float4 v = *(const float4*)(hidden + (size_t)b * H_ + h0 + c);
        ushort4 o; o.x = f2b(v.x); o.y = f2b(v.y); o.z = f2b(v.z); o.w = f2b(v.w);
        *(ushort4*)&A_lds[b][c0 + c] = o;
      }
    }
  }
  __syncthreads();
  const float* Bw = z ? W_hh : W_ih;
  float* C = z ? ghp : gip;
  int wave = tid >> 6, lane = tid & 63, l15 = lane & 15, l16 = lane >> 4;
  int col = nb * 64 + wave * 16 + l15;
  const float* bp = Bw + (size_t)col * 1024 + kc * 128 + l16 * 8;
  f32x4 acc0 = {0.f,0.f,0.f,0.f}, acc1 = {0.f,0.f,0.f,0.f};
  #pragma unroll
  for (int k = 0; k < 128; k += 32) {
    bf16x8 a0 = *(const bf16x8*)&A_lds[l15][k + l16 * 8];
    bf16x8 a1 = *(const bf16x8*)&A_lds[16 + l15][k + l16 * 8];
    float4 bv0 = *(const float4*)(bp + k);
    float4 bv1 = *(const float4*)(bp + k + 4);
    bf16x8 bb;
    bb[0] = (short)f2b(bv0.x); bb[1] = (short)f2b(bv0.y);
    bb[2] = (short)f2b(bv0.z); bb[3] = (short)f2b(bv0.w);
    bb[4] = (short)f2b(bv1.x); bb[5] = (short)f2b(bv1.y);
    bb[6] = (short)f2b(bv1.z); bb[7] = (short)f2b(bv1.w);
    acc0 = __builtin_amdgcn_mfma_f32_16x16x32_bf16(a0, bb, acc0, 0, 0, 0);
    acc1 = __builtin_amdgcn_mfma_f32_16x16x32_bf16(a1, bb, acc1, 0, 0, 0);
  }
  #pragma unroll
  for (int r = 0; r < 4; ++r) {
    int m = l16 * 4 + r;
    C[(size_t)(kc * 32 + m) * 3072 + col] = acc0[r];
    C[(size_t)(kc * 32 + 16 + m) * 3072 + col] = acc1[r];
  }
}

// ---------- GRU gates + h_new (8 chunks) ----------
__global__ void gates_kernel(const float* __restrict__ gip, const float* __restrict__ ghp,
                             const float* __restrict__ b_ih, const float* __restrict__ b_hh,
                             const float* __restrict__ hidden, float* __restrict__ hnew_out,
                             unsigned short* __restrict__ hr_bf) {
  int i = blockIdx.x * 256 + threadIdx.x;   // 32768
  int b = i >> 10, h = i & 1023;
  float g[6];
  #pragma unroll
  for (int t = 0; t < 3; ++t) {
    int j = h + t * H_;
    float vi = b_ih[j], vh = b_hh[j];
    #pragma unroll
    for (int kc = 0; kc < 8; ++kc) {
      vi += gip[(size_t)(kc * B_ + b) * 3072 + j];
      vh += ghp[(size_t)(kc * B_ + b) * 3072 + j];
    }
    g[t] = vi; g[3 + t] = vh;
  }
  float r = 1.f / (1.f + expf(-(g[0] + g[3])));
  float z = 1.f / (1.f + expf(-(g[1] + g[4])));
  float n = tanhf(g[2] + r * g[5]);
  float hv = (1.f - z) * n + z * hidden[i];
  hnew_out[i] = hv;
  hr_bf[i] = f2b(hv > 0.f ? hv : 0.f);
}

// ---------- final skinny GEMM: out[32,V] = hr_bf @ W_fc^T + b_fc ----------
__global__ __launch_bounds__(256) void fc_gemm(
    const unsigned short* __restrict__ A, const float* __restrict__ Bw,
    float* __restrict__ C, const float* __restrict__ bias) {
  const int N = V_, K = 1024;
  int n0 = blockIdx.x * 64;
  int wave = threadIdx.x >> 6, lane = threadIdx.x & 63;
  int l15 = lane & 15, l16 = lane >> 4;
  int col = n0 + wave * 16 + l15;
  int vclamp = col < N ? col : N - 1;
  const unsigned short* a0p = A + l15 * K + l16 * 8;
  const unsigned short* a1p = A + (16 + l15) * K + l16 * 8;
  const float* bp = Bw + (size_t)vclamp * K + l16 * 8;
  f32x4 acc0 = {0.f,0.f,0.f,0.f}, acc1 = {0.f,0.f,0.f,0.f};
  #pragma unroll 4
  for (int k = 0; k < K; k += 32) {
    bf16x8 a0 = *(const bf16x8*)(a0p + k);
    bf16x8 a1 = *(const bf16x8*)(a1p + k);
    float4 bv0 = *(const float4*)(bp + k);
    float4 bv1 = *(const float4*)(bp + k + 4);
    bf16x8 bb;
    bb[0] = (short)f2b(bv0.x); bb[1] = (short)f2b(bv0.y);
    bb[2] = (short)f2b(bv0.z); bb[3] = (short)f2b(bv0.w);
    bb[4] = (short)f2b(bv1.x); bb[5] = (short)f2b(bv1.y);
    bb[6] = (short)f2b(bv1.z); bb[7] = (short)f2b(bv1.w);
    acc0 = __builtin_amdgcn_mfma_f32_16x16x32_bf16(a0, bb, acc0, 0, 0, 0);
    acc1 = __builtin_amdgcn_mfma_f32_16x16x32_bf16(a1, bb, acc1, 0, 0, 0);
  }
  if (col < N) {
    float bv = bias[col];
    #pragma unroll
    for (int r = 0; r < 4; ++r) {
      int m = l16 * 4 + r;
      C[(size_t)m * N + col] = acc0[r] + bv;
      C[(size_t)(16 + m) * N + col] = acc1[r] + bv;
    }
  }
}

extern "C" void kernel_launch(void* const* d_in, const int* in_sizes, int n_in,
                              void* d_out, int out_size, void* d_ws, size_t ws_size,
                              hipStream_t stream) {
  const int*   word   = (const int*)  d_in[0];
  const float* hidden = (const float*)d_in[1];
  const float* enc    = (const float*)d_in[2];
  const float* emb    = (const float*)d_in[3];
  const float* W_a1   = (const float*)d_in[4];
  const float* b_a1   = (const float*)d_in[5];
  const float* W_a2   = (const float*)d_in[6];
  const float* b_c    = (const float*)d_in[9];
  const float* W_c    = (const float*)d_in[8];
  const float* W_ih   = (const float*)d_in[10];
  const float* W_hh   = (const float*)d_in[11];
  const float* b_ih   = (const float*)d_in[12];
  const float* b_hh   = (const float*)d_in[13];
  const float* W_fc   = (const float*)d_in[14];
  const float* b_fc   = (const float*)d_in[15];
  float* out = (float*)d_out;

  if (ws_size < 73596928ull) return;  // loud failure

  char* ws = (char*)d_ws;
  unsigned short* enc_bf   = (unsigned short*)(ws + 0);
  float*          gip      = (float*)         (ws + 0);
  float*          ghp      = (float*)         (ws + 3145728);
  unsigned short* wa1_bf   = (unsigned short*)(ws + 67108864);
  float*          xp       = (float*)         (ws + 67108864);
  float*          part2    = (float*)         (ws + 69206016);
  float*          partials = (float*)         (ws + 69337088);
  float*          ctxp     = (float*)         (ws + 71434240);
  unsigned short* hr_bf    = (unsigned short*)(ws + 73531392);

  prologue_kernel<<<dim3(17408), dim3(256), 0, stream>>>(enc, enc_bf, W_a1, hidden, b_a1,
                                                         wa1_bf, part2);
  scores_nolds<<<dim3(8, 256), dim3(256), 0, stream>>>(enc_bf, wa1_bf, part2, W_a2, partials);
  smctx_kernel<<<dim3(16, 32), dim3(256), 0, stream>>>(partials, enc_bf, ctxp);
  wc_gemm<<<dim3(16, 16), dim3(256), 0, stream>>>(word, emb, ctxp, W_c, xp);
  ihhh_gemm<<<dim3(48, 8, 2), dim3(256), 0, stream>>>(xp, b_c, hidden, W_ih, W_hh, gip, ghp);
  gates_kernel<<<dim3(128), dim3(256), 0, stream>>>(gip, ghp, b_ih, b_hh, hidden,
                                                    out + (size_t)B_ * V_, hr_bf);
  fc_gemm<<<dim3(786), dim3(256), 0, stream>>>(hr_bf, W_fc, out, b_fc);
}

// Round 11
// 288.214 us; speedup vs baseline: 1.5598x; 1.5598x over previous
//
#include <hip/hip_runtime.h>

#define B_  32
#define S_  1024
#define H_  1024
#define V_  50257

typedef __attribute__((ext_vector_type(8))) short bf16x8;
typedef __attribute__((ext_vector_type(4))) float f32x4;
typedef __attribute__((ext_vector_type(8))) unsigned short u16x8;

__device__ __forceinline__ unsigned short f2b(float f) {
  union { float f; unsigned u; } v; v.f = f;
  unsigned r = 0x7FFFu + ((v.u >> 16) & 1u);
  return (unsigned short)((v.u + r) >> 16);
}
__device__ __forceinline__ float b2f(unsigned short h) {
  union { unsigned u; float f; } v; v.u = ((unsigned)h) << 16;
  return v.f;
}

__device__ __forceinline__ void async16(void* lds, const void* g) {
  typedef __attribute__((address_space(3))) void as3_void;
  typedef __attribute__((address_space(1))) void as1_void;
  as3_void* l = (as3_void*)(unsigned)(unsigned long long)lds;
  const as1_void* s = (const as1_void*)(unsigned long long)g;
  __builtin_amdgcn_global_load_lds(s, l, 16, 0, 0);
}

// ---------- fused prologue: enc conv (blocks 0..16383) + wa1 conv/part2 ----------
__global__ void prologue_kernel(const float* __restrict__ enc, unsigned short* __restrict__ enc_bf,
                                const float* __restrict__ wa1, const float* __restrict__ hidden,
                                const float* __restrict__ b_a1,
                                unsigned short* __restrict__ wa1_bf, float* __restrict__ part2) {
  __shared__ float wrow[H_];
  int tid = threadIdx.x;
  if (blockIdx.x < 16384) {
    size_t i = ((size_t)blockIdx.x * 256 + tid) * 8;
    float4 v0 = *(const float4*)(enc + i);
    float4 v1 = *(const float4*)(enc + i + 4);
    u16x8 o;
    o[0]=f2b(v0.x); o[1]=f2b(v0.y); o[2]=f2b(v0.z); o[3]=f2b(v0.w);
    o[4]=f2b(v1.x); o[5]=f2b(v1.y); o[6]=f2b(v1.z); o[7]=f2b(v1.w);
    *(u16x8*)(enc_bf + i) = o;
    return;
  }
  int h = blockIdx.x - 16384;
  {
    int c = tid * 4;
    float4 v = *(const float4*)(wa1 + (size_t)h * 2048 + c);
    ushort4 o;
    o.x = f2b(v.x); o.y = f2b(v.y); o.z = f2b(v.z); o.w = f2b(v.w);
    *(ushort4*)(wa1_bf + (size_t)h * 1024 + c) = o;
  }
  {
    int c = tid * 4;
    float4 v = *(const float4*)(wa1 + (size_t)h * 2048 + 1024 + c);
    wrow[c] = v.x; wrow[c+1] = v.y; wrow[c+2] = v.z; wrow[c+3] = v.w;
  }
  __syncthreads();
  int wave = tid >> 6, lane = tid & 63;
  float bias = b_a1[h];
  for (int bb = 0; bb < 8; ++bb) {
    int b = wave * 8 + bb;
    float acc = 0.f;
    for (int k = lane; k < H_; k += 64) acc += wrow[k] * hidden[b * H_ + k];
    #pragma unroll
    for (int off = 32; off; off >>= 1) acc += __shfl_xor(acc, off);
    if (lane == 0) part2[b * H_ + h] = acc + bias;
  }
}

// ---------- scores GEMM v5: m97 structure + XCD-aware block remap ----------
// r9-proven kernel (122us, conflicts=0). NEW: bijective remap so the 8 bn-blocks sharing
// one A-tile land on the SAME XCD (default dispatch round-robins id%8 across XCDs [T1]):
//   id -> xcd=id&7, s=id>>3, bm=(s>>3)*8+xcd, bn=s&7
// XCD x gets bm with bm%8==x, all 8 bn each -> A-tile fetched once per XCD (64MB total),
// B (2MB) L2-resident per XCD. Predicted FETCH 265MB -> ~90MB.
__global__ __launch_bounds__(256) void scores_m97(
    const unsigned short* __restrict__ A,   // enc_bf [32768][1024]
    const unsigned short* __restrict__ Bm,  // wa1_bf [1024][1024]
    const float* __restrict__ part2,        // [32][1024]
    const float* __restrict__ wa2,          // [1024]
    float* __restrict__ partials)           // [32768][16]
{
  __shared__ __align__(16) unsigned short As[4096];  // 8KB
  __shared__ __align__(16) unsigned short Bs[4096];  // 8KB
  const int tid = threadIdx.x;
  const int wave = tid >> 6, lane = tid & 63;
  const int wr = wave >> 1, wc = wave & 1;
  const int l15 = lane & 15, l16 = lane >> 4;

  // XCD-aware remap (bijective: 2048 blocks, 2048%8==0)
  const int id = blockIdx.x;
  const int xcd = id & 7;
  const int s = id >> 3;
  const int bm = (s >> 3) * 8 + xcd;   // 0..255
  const int bn = s & 7;                // 0..7

  const unsigned short* Abase = A  + (size_t)(bm * 128) * 1024;
  const unsigned short* Bbase = Bm + (size_t)(bn * 128) * 1024;

  // staging: thread tid covers physical granules P = tid*16 (rows 0..63) and P+4096 (rows 64..127)
  const int Lc = tid * 16;                               // 0..4095
  const int r0 = Lc >> 6;                                // row 0..63
  const int cb0 = (Lc & 63) ^ (((r0 >> 1) & 3) << 4);    // inverse-swizzled col bytes
  const int ce0 = cb0 >> 1;                              // bf16 elements

  f32x4 acc[4][4];
  #pragma unroll
  for (int mi = 0; mi < 4; ++mi)
    #pragma unroll
    for (int ni = 0; ni < 4; ++ni) acc[mi][ni] = (f32x4){0.f, 0.f, 0.f, 0.f};
  bf16x8 af[4], bfr[4];

  for (int kt = 0; kt < 1024; kt += 32) {
    async16((char*)As + Lc,        Abase + (size_t)r0 * 1024 + kt + ce0);
    async16((char*)As + Lc + 4096, Abase + (size_t)(r0 + 64) * 1024 + kt + ce0);
    async16((char*)Bs + Lc,        Bbase + (size_t)r0 * 1024 + kt + ce0);
    async16((char*)Bs + Lc + 4096, Bbase + (size_t)(r0 + 64) * 1024 + kt + ce0);
    asm volatile("s_waitcnt vmcnt(0)" ::: "memory");
    __syncthreads();
    #pragma unroll
    for (int mi = 0; mi < 4; ++mi) {
      int ar = wr * 64 + mi * 16 + l15;
      int L = ar * 64 + l16 * 16;
      af[mi] = *(const bf16x8*)((const char*)As + (L ^ (((ar >> 1) & 3) << 4)));
    }
    #pragma unroll
    for (int ni = 0; ni < 4; ++ni) {
      int br = wc * 64 + ni * 16 + l15;
      int L = br * 64 + l16 * 16;
      bfr[ni] = *(const bf16x8*)((const char*)Bs + (L ^ (((br >> 1) & 3) << 4)));
    }
    #pragma unroll
    for (int mi = 0; mi < 4; ++mi)
      #pragma unroll
      for (int ni = 0; ni < 4; ++ni)
        acc[mi][ni] = __builtin_amdgcn_mfma_f32_16x16x32_bf16(af[mi], bfr[ni], acc[mi][ni], 0, 0, 0);
    __syncthreads();
  }

  // fused epilogue: partials[row][bn*2+wc] = sum over this 64-col group of wa2*tanh(acc+part2)
  const int b = bm >> 3;   // 128 rows/tile, 1024 rows/batch
  float w2[4], p2[4];
  #pragma unroll
  for (int ni = 0; ni < 4; ++ni) {
    int col = bn * 128 + wc * 64 + ni * 16 + l15;
    w2[ni] = wa2[col];
    p2[ni] = part2[b * H_ + col];
  }
  #pragma unroll
  for (int mi = 0; mi < 4; ++mi) {
    #pragma unroll
    for (int r = 0; r < 4; ++r) {
      float s2 = 0.f;
      #pragma unroll
      for (int ni = 0; ni < 4; ++ni)
        s2 += w2[ni] * tanhf(acc[mi][ni][r] + p2[ni]);
      s2 += __shfl_xor(s2, 1); s2 += __shfl_xor(s2, 2);
      s2 += __shfl_xor(s2, 4); s2 += __shfl_xor(s2, 8);
      if (l15 == 0) {
        int row = bm * 128 + wr * 64 + mi * 16 + l16 * 4 + r;
        partials[(size_t)row * 16 + bn * 2 + wc] = s2;
      }
    }
  }
}

// ---------- fused softmax + context chunk: block (sc, b) ----------
__global__ __launch_bounds__(256) void smctx_kernel(
    const float* __restrict__ partials, const unsigned short* __restrict__ encbf,
    float* __restrict__ ctxp) {
  int sc = blockIdx.x, b = blockIdx.y, tid = threadIdx.x;
  int lane = tid & 63, wid = tid >> 6;
  __shared__ float att[1024];
  __shared__ float red[4];
  float scv[4];
  float mx = -1e30f;
  #pragma unroll
  for (int j = 0; j < 4; ++j) {
    int r = tid * 4 + j;
    const float4* p = (const float4*)(partials + ((size_t)b * 1024 + r) * 16);
    float s = 0.f;
    #pragma unroll
    for (int i = 0; i < 4; ++i) { float4 v = p[i]; s += v.x + v.y + v.z + v.w; }
    scv[j] = s; mx = fmaxf(mx, s);
  }
  #pragma unroll
  for (int off = 32; off; off >>= 1) mx = fmaxf(mx, __shfl_xor(mx, off));
  if (lane == 0) red[wid] = mx;
  __syncthreads();
  float M = fmaxf(fmaxf(red[0], red[1]), fmaxf(red[2], red[3]));
  float ssum = 0.f;
  #pragma unroll
  for (int j = 0; j < 4; ++j) { float e = expf(scv[j] - M); att[tid*4+j] = e; ssum += e; }
  #pragma unroll
  for (int off = 32; off; off >>= 1) ssum += __shfl_xor(ssum, off);
  __syncthreads();
  if (lane == 0) red[wid] = ssum;
  __syncthreads();
  float inv = 1.f / (red[0] + red[1] + red[2] + red[3]);
  int h4 = tid * 4;
  float a0 = 0, a1 = 0, a2 = 0, a3 = 0;
  const unsigned short* base = encbf + (size_t)b * S_ * H_ + h4;
  #pragma unroll 4
  for (int i = 0; i < 64; ++i) {
    float w = att[sc * 64 + i] * inv;
    ushort4 ev = *(const ushort4*)(base + (size_t)(sc * 64 + i) * H_);
    a0 += w * b2f(ev.x); a1 += w * b2f(ev.y); a2 += w * b2f(ev.z); a3 += w * b2f(ev.w);
  }
  float4 o = {a0, a1, a2, a3};
  *(float4*)(ctxp + (size_t)(sc * B_ + b) * H_ + h4) = o;
}

// ---------- W_c GEMM with inline ec construction: block (nb, kc) ----------
__global__ __launch_bounds__(256) void wc_gemm(
    const int* __restrict__ word, const float* __restrict__ emb,
    const float* __restrict__ ctxp, const float* __restrict__ Wc,
    float* __restrict__ xp) {
  int nb = blockIdx.x, kc = blockIdx.y, tid = threadIdx.x;
  __shared__ unsigned short A_lds[32][136];
  {
    int b = tid >> 3, cg = tid & 7;
    int c0 = cg * 16;
    if (kc < 8) {
      int w = word[b];
      const float* er = emb + (size_t)w * H_ + kc * 128 + c0;
      #pragma unroll
      for (int c = 0; c < 16; c += 4) {
        float4 v = *(const float4*)(er + c);
        ushort4 o; o.x = f2b(v.x); o.y = f2b(v.y); o.z = f2b(v.z); o.w = f2b(v.w);
        *(ushort4*)&A_lds[b][c0 + c] = o;
      }
    } else {
      int h0 = (kc - 8) * 128 + c0;
      #pragma unroll
      for (int c = 0; c < 16; c += 4) {
        float s0 = 0, s1 = 0, s2 = 0, s3 = 0;
        #pragma unroll
        for (int sc = 0; sc < 16; ++sc) {
          float4 v = *(const float4*)(ctxp + ((size_t)(sc * B_ + b)) * H_ + h0 + c);
          s0 += v.x; s1 += v.y; s2 += v.z; s3 += v.w;
        }
        ushort4 o; o.x = f2b(s0); o.y = f2b(s1); o.z = f2b(s2); o.w = f2b(s3);
        *(ushort4*)&A_lds[b][c0 + c] = o;
      }
    }
  }
  __syncthreads();
  int wave = tid >> 6, lane = tid & 63, l15 = lane & 15, l16 = lane >> 4;
  int col = nb * 64 + wave * 16 + l15;
  const float* bp = Wc + (size_t)col * 2048 + kc * 128 + l16 * 8;
  f32x4 acc0 = {0.f,0.f,0.f,0.f}, acc1 = {0.f,0.f,0.f,0.f};
  #pragma unroll
  for (int k = 0; k < 128; k += 32) {
    bf16x8 a0 = *(const bf16x8*)&A_lds[l15][k + l16 * 8];
    bf16x8 a1 = *(const bf16x8*)&A_lds[16 + l15][k + l16 * 8];
    float4 bv0 = *(const float4*)(bp + k);
    float4 bv1 = *(const float4*)(bp + k + 4);
    bf16x8 bb;
    bb[0] = (short)f2b(bv0.x); bb[1] = (short)f2b(bv0.y);
    bb[2] = (short)f2b(bv0.z); bb[3] = (short)f2b(bv0.w);
    bb[4] = (short)f2b(bv1.x); bb[5] = (short)f2b(bv1.y);
    bb[6] = (short)f2b(bv1.z); bb[7] = (short)f2b(bv1.w);
    acc0 = __builtin_amdgcn_mfma_f32_16x16x32_bf16(a0, bb, acc0, 0, 0, 0);
    acc1 = __builtin_amdgcn_mfma_f32_16x16x32_bf16(a1, bb, acc1, 0, 0, 0);
  }
  #pragma unroll
  for (int r = 0; r < 4; ++r) {
    int m = l16 * 4 + r;
    xp[(size_t)(kc * 32 + m) * H_ + col] = acc0[r];
    xp[(size_t)(kc * 32 + 16 + m) * H_ + col] = acc1[r];
  }
}

// ---------- fused W_ih / W_hh GEMM with inline x / hprev construction ----------
__global__ __launch_bounds__(256) void ihhh_gemm(
    const float* __restrict__ xp, const float* __restrict__ b_c,
    const float* __restrict__ hidden,
    const float* __restrict__ W_ih, const float* __restrict__ W_hh,
    float* __restrict__ gip, float* __restrict__ ghp) {
  int nb = blockIdx.x, kc = blockIdx.y, z = blockIdx.z, tid = threadIdx.x;
  __shared__ unsigned short A_lds[32][136];
  {
    int b = tid >> 3, cg = tid & 7;
    int c0 = cg * 16;
    int h0 = kc * 128 + c0;
    if (z == 0) {
      #pragma unroll
      for (int c = 0; c < 16; c += 4) {
        float4 bias = *(const float4*)(b_c + h0 + c);
        float s0 = bias.x, s1 = bias.y, s2 = bias.z, s3 = bias.w;
        #pragma unroll
        for (int sc = 0; sc < 16; ++sc) {
          float4 v = *(const float4*)(xp + ((size_t)(sc * B_ + b)) * H_ + h0 + c);
          s0 += v.x; s1 += v.y; s2 += v.z; s3 += v.w;
        }
        ushort4 o;
        o.x = f2b(fmaxf(s0, 0.f)); o.y = f2b(fmaxf(s1, 0.f));
        o.z = f2b(fmaxf(s2, 0.f)); o.w = f2b(fmaxf(s3, 0.f));
        *(ushort4*)&A_lds[b][c0 + c] = o;
      }
    } else {
      #pragma unroll
      for (int c = 0; c < 16; c += 4) {
        float4 v = *(const float4*)(hidden + (size_t)b * H_ + h0 + c);
        ushort4 o; o.x = f2b(v.x); o.y = f2b(v.y); o.z = f2b(v.z); o.w = f2b(v.w);
        *(ushort4*)&A_lds[b][c0 + c] = o;
      }
    }
  }
  __syncthreads();
  const float* Bw = z ? W_hh : W_ih;
  float* C = z ? ghp : gip;
  int wave = tid >> 6, lane = tid & 63, l15 = lane & 15, l16 = lane >> 4;
  int col = nb * 64 + wave * 16 + l15;
  const float* bp = Bw + (size_t)col * 1024 + kc * 128 + l16 * 8;
  f32x4 acc0 = {0.f,0.f,0.f,0.f}, acc1 = {0.f,0.f,0.f,0.f};
  #pragma unroll
  for (int k = 0; k < 128; k += 32) {
    bf16x8 a0 = *(const bf16x8*)&A_lds[l15][k + l16 * 8];
    bf16x8 a1 = *(const bf16x8*)&A_lds[16 + l15][k + l16 * 8];
    float4 bv0 = *(const float4*)(bp + k);
    float4 bv1 = *(const float4*)(bp + k + 4);
    bf16x8 bb;
    bb[0] = (short)f2b(bv0.x); bb[1] = (short)f2b(bv0.y);
    bb[2] = (short)f2b(bv0.z); bb[3] = (short)f2b(bv0.w);
    bb[4] = (short)f2b(bv1.x); bb[5] = (short)f2b(bv1.y);
    bb[6] = (short)f2b(bv1.z); bb[7] = (short)f2b(bv1.w);
    acc0 = __builtin_amdgcn_mfma_f32_16x16x32_bf16(a0, bb, acc0, 0, 0, 0);
    acc1 = __builtin_amdgcn_mfma_f32_16x16x32_bf16(a1, bb, acc1, 0, 0, 0);
  }
  #pragma unroll
  for (int r = 0; r < 4; ++r) {
    int m = l16 * 4 + r;
    C[(size_t)(kc * 32 + m) * 3072 + col] = acc0[r];
    C[(size_t)(kc * 32 + 16 + m) * 3072 + col] = acc1[r];
  }
}

// ---------- GRU gates + h_new (8 chunks) ----------
__global__ void gates_kernel(const float* __restrict__ gip, const float* __restrict__ ghp,
                             const float* __restrict__ b_ih, const float* __restrict__ b_hh,
                             const float* __restrict__ hidden, float* __restrict__ hnew_out,
                             unsigned short* __restrict__ hr_bf) {
  int i = blockIdx.x * 256 + threadIdx.x;   // 32768
  int b = i >> 10, h = i & 1023;
  float g[6];
  #pragma unroll
  for (int t = 0; t < 3; ++t) {
    int j = h + t * H_;
    float vi = b_ih[j], vh = b_hh[j];
    #pragma unroll
    for (int kc = 0; kc < 8; ++kc) {
      vi += gip[(size_t)(kc * B_ + b) * 3072 + j];
      vh += ghp[(size_t)(kc * B_ + b) * 3072 + j];
    }
    g[t] = vi; g[3 + t] = vh;
  }
  float r = 1.f / (1.f + expf(-(g[0] + g[3])));
  float z = 1.f / (1.f + expf(-(g[1] + g[4])));
  float n = tanhf(g[2] + r * g[5]);
  float hv = (1.f - z) * n + z * hidden[i];
  hnew_out[i] = hv;
  hr_bf[i] = f2b(hv > 0.f ? hv : 0.f);
}

// ---------- final skinny GEMM: out[32,V] = hr_bf @ W_fc^T + b_fc ----------
__global__ __launch_bounds__(256) void fc_gemm(
    const unsigned short* __restrict__ A, const float* __restrict__ Bw,
    float* __restrict__ C, const float* __restrict__ bias) {
  const int N = V_, K = 1024;
  int n0 = blockIdx.x * 64;
  int wave = threadIdx.x >> 6, lane = threadIdx.x & 63;
  int l15 = lane & 15, l16 = lane >> 4;
  int col = n0 + wave * 16 + l15;
  int vclamp = col < N ? col : N - 1;
  const unsigned short* a0p = A + l15 * K + l16 * 8;
  const unsigned short* a1p = A + (16 + l15) * K + l16 * 8;
  const float* bp = Bw + (size_t)vclamp * K + l16 * 8;
  f32x4 acc0 = {0.f,0.f,0.f,0.f}, acc1 = {0.f,0.f,0.f,0.f};
  #pragma unroll 4
  for (int k = 0; k < K; k += 32) {
    bf16x8 a0 = *(const bf16x8*)(a0p + k);
    bf16x8 a1 = *(const bf16x8*)(a1p + k);
    float4 bv0 = *(const float4*)(bp + k);
    float4 bv1 = *(const float4*)(bp + k + 4);
    bf16x8 bb;
    bb[0] = (short)f2b(bv0.x); bb[1] = (short)f2b(bv0.y);
    bb[2] = (short)f2b(bv0.z); bb[3] = (short)f2b(bv0.w);
    bb[4] = (short)f2b(bv1.x); bb[5] = (short)f2b(bv1.y);
    bb[6] = (short)f2b(bv1.z); bb[7] = (short)f2b(bv1.w);
    acc0 = __builtin_amdgcn_mfma_f32_16x16x32_bf16(a0, bb, acc0, 0, 0, 0);
    acc1 = __builtin_amdgcn_mfma_f32_16x16x32_bf16(a1, bb, acc1, 0, 0, 0);
  }
  if (col < N) {
    float bv = bias[col];
    #pragma unroll
    for (int r = 0; r < 4; ++r) {
      int m = l16 * 4 + r;
      C[(size_t)m * N + col] = acc0[r] + bv;
      C[(size_t)(16 + m) * N + col] = acc1[r] + bv;
    }
  }
}

extern "C" void kernel_launch(void* const* d_in, const int* in_sizes, int n_in,
                              void* d_out, int out_size, void* d_ws, size_t ws_size,
                              hipStream_t stream) {
  const int*   word   = (const int*)  d_in[0];
  const float* hidden = (const float*)d_in[1];
  const float* enc    = (const float*)d_in[2];
  const float* emb    = (const float*)d_in[3];
  const float* W_a1   = (const float*)d_in[4];
  const float* b_a1   = (const float*)d_in[5];
  const float* W_a2   = (const float*)d_in[6];
  const float* b_c    = (const float*)d_in[9];
  const float* W_c    = (const float*)d_in[8];
  const float* W_ih   = (const float*)d_in[10];
  const float* W_hh   = (const float*)d_in[11];
  const float* b_ih   = (const float*)d_in[12];
  const float* b_hh   = (const float*)d_in[13];
  const float* W_fc   = (const float*)d_in[14];
  const float* b_fc   = (const float*)d_in[15];
  float* out = (float*)d_out;

  if (ws_size < 73596928ull) return;  // loud failure

  char* ws = (char*)d_ws;
  unsigned short* enc_bf   = (unsigned short*)(ws + 0);
  float*          gip      = (float*)         (ws + 0);
  float*          ghp      = (float*)         (ws + 3145728);
  unsigned short* wa1_bf   = (unsigned short*)(ws + 67108864);
  float*          xp       = (float*)         (ws + 67108864);
  float*          part2    = (float*)         (ws + 69206016);
  float*          partials = (float*)         (ws + 69337088);
  float*          ctxp     = (float*)         (ws + 71434240);
  unsigned short* hr_bf    = (unsigned short*)(ws + 73531392);

  prologue_kernel<<<dim3(17408), dim3(256), 0, stream>>>(enc, enc_bf, W_a1, hidden, b_a1,
                                                         wa1_bf, part2);
  scores_m97<<<dim3(2048), dim3(256), 0, stream>>>(enc_bf, wa1_bf, part2, W_a2, partials);
  smctx_kernel<<<dim3(16, 32), dim3(256), 0, stream>>>(partials, enc_bf, ctxp);
  wc_gemm<<<dim3(16, 16), dim3(256), 0, stream>>>(word, emb, ctxp, W_c, xp);
  ihhh_gemm<<<dim3(48, 8, 2), dim3(256), 0, stream>>>(xp, b_c, hidden, W_ih, W_hh, gip, ghp);
  gates_kernel<<<dim3(128), dim3(256), 0, stream>>>(gip, ghp, b_ih, b_hh, hidden,
                                                    out + (size_t)B_ * V_, hr_bf);
  fc_gemm<<<dim3(786), dim3(256), 0, stream>>>(hr_bf, W_fc, out, b_fc);
}